// Round 5
// baseline (120.092 us; speedup 1.0000x reference)
//
#include <hip/hip_runtime.h>

// BEV pooling: out[bin, c] = sum over points i with ranks_bev[i]==bin of
//                            depth_flat[ranks_depth[i]] * feat_flat[ranks_feat[i], c]
// ranks_bev is SORTED. Two phases:
//   1) seg[b] = lower_bound(rb, b) via vectorized boundary detection (int4)
//   2) ONE WAVE PER BIN, 16 point-slots x 4 channel-lanes (transaction-optimal:
//      4 lanes x 16B = exactly one 64B line per slot per feat instruction).
//      DUAL-STREAM loop — 32 points/iter as two independent 16-point streams
//      (A: i, i+32...; B: i+16, i+48...). All 12 value loads issue in one body
//      so a single ~250cy L2 window covers 32 points; FMA-A runs under B's
//      outstanding loads (counted vmcnt). Stream B is branchless (index
//      clamped to hi-1, weight zero-masked; B subset of A's exec mask).
//      Per-lane FMA order is unchanged (i, i+16, i+32, ...) -> identical
//      rounding to the previous version.
//      Epilogue (proven R3 win): LDS transpose-reduce — 5 ds_write_b128 +
//      8 ds_read_b128 + 7 float4 adds + one shfl_xor(32), per-wave-private.
// (R4 bench was an infra failure — container died twice, kernel never ran.
//  Same signature as R2 which passed unchanged on retry. Audited again for
//  hang/fault hazards: none. Resubmitting unchanged.)

#define CHN 80
#define SSTRIDE 84   // floats per slot row in LDS: 80 + 4 pad (bank spread, 16B-aligned)

__global__ __launch_bounds__(256)
void seg_starts_kernel(const int* __restrict__ rb, int* __restrict__ seg,
                       int P, int total_bev) {
    int q = blockIdx.x * blockDim.x + threadIdx.x;   // quad index
    int i4 = q * 4;
    if (i4 >= P) return;
    const int4 v = *reinterpret_cast<const int4*>(rb + i4);
    int prev = (i4 == 0) ? -1 : rb[i4 - 1];
    int cur;
    cur = v.x; for (int b = prev + 1; b <= cur; ++b) seg[b] = i4 + 0; prev = cur;
    cur = v.y; for (int b = prev + 1; b <= cur; ++b) seg[b] = i4 + 1; prev = cur;
    cur = v.z; for (int b = prev + 1; b <= cur; ++b) seg[b] = i4 + 2; prev = cur;
    cur = v.w; for (int b = prev + 1; b <= cur; ++b) seg[b] = i4 + 3; prev = cur;
    if (i4 + 4 >= P) {
        for (int b = prev + 1; b <= total_bev; ++b) seg[b] = P;
    }
}

__global__ __launch_bounds__(256)
void bev_pool_kernel(const float* __restrict__ depth,
                     const float* __restrict__ feat,
                     const int* __restrict__ rd,
                     const int* __restrict__ rf,
                     const int* __restrict__ seg,
                     float* __restrict__ out,
                     int total_bev) {
    __shared__ float lds_buf[4][16 * SSTRIDE];       // per-wave-private 16x84 floats

    const int wave = threadIdx.x >> 6;               // 4 waves per block
    const int lane = threadIdx.x & 63;
    const int bin = blockIdx.x * 4 + wave;
    if (bin >= total_bev) return;

    const int slot = lane >> 2;                      // 0..15 point slot
    const int ll   = lane & 3;                       // 0..3 channel sub-lane

    const int lo = seg[bin];
    const int hi = seg[bin + 1];

    float4 a0 = make_float4(0.f, 0.f, 0.f, 0.f);
    float4 a1 = a0, a2 = a0, a3 = a0, a4 = a0;

    int iA = lo + slot;                              // stream A: i, i+32, ...
    bool vA = iA < hi;
    if (vA) {                                        // per-lane; B subset of A
        const int last = hi - 1;                     // clamp target (>= lo >= 0)
        const int iB0 = iA + 16;                     // stream B: i+16, i+48, ...
        bool vB = iB0 < hi;
        const int clB0 = vB ? iB0 : last;
        int diA = rd[iA],   fiA = rf[iA];
        int diB = rd[clB0], fiB = rf[clB0];

        do {
            // --- prefetch next-iteration indices (clamped, branchless) ---
            const int nA  = iA + 32;
            const int nB  = nA + 16;
            const bool nvA = nA < hi;
            const bool nvB = nB < hi;
            const int cnA = nvA ? nA : last;
            const int cnB = nvB ? nB : last;
            const int ndiA = rd[cnA], nfiA = rf[cnA];
            const int ndiB = rd[cnB], nfiB = rf[cnB];

            // --- issue ALL 12 value loads before any FMA waits ---
            const float dAv = depth[diA];
            const float4* frA = reinterpret_cast<const float4*>(feat + (size_t)fiA * CHN) + ll;
            const float4 fa0 = frA[0], fa1 = frA[4], fa2 = frA[8],
                         fa3 = frA[12], fa4 = frA[16];
            const float dBv = depth[diB];
            const float4* frB = reinterpret_cast<const float4*>(feat + (size_t)fiB * CHN) + ll;
            const float4 fb0 = frB[0], fb1 = frB[4], fb2 = frB[8],
                         fb3 = frB[12], fb4 = frB[16];

            // --- FMA stream A (overlaps B's outstanding loads) ---
            a0.x += dAv*fa0.x; a0.y += dAv*fa0.y; a0.z += dAv*fa0.z; a0.w += dAv*fa0.w;
            a1.x += dAv*fa1.x; a1.y += dAv*fa1.y; a1.z += dAv*fa1.z; a1.w += dAv*fa1.w;
            a2.x += dAv*fa2.x; a2.y += dAv*fa2.y; a2.z += dAv*fa2.z; a2.w += dAv*fa2.w;
            a3.x += dAv*fa3.x; a3.y += dAv*fa3.y; a3.z += dAv*fa3.z; a3.w += dAv*fa3.w;
            a4.x += dAv*fa4.x; a4.y += dAv*fa4.y; a4.z += dAv*fa4.z; a4.w += dAv*fa4.w;

            // --- FMA stream B (zero-masked when this lane's B point is past hi) ---
            const float wB = vB ? dBv : 0.f;
            a0.x += wB*fb0.x; a0.y += wB*fb0.y; a0.z += wB*fb0.z; a0.w += wB*fb0.w;
            a1.x += wB*fb1.x; a1.y += wB*fb1.y; a1.z += wB*fb1.z; a1.w += wB*fb1.w;
            a2.x += wB*fb2.x; a2.y += wB*fb2.y; a2.z += wB*fb2.z; a2.w += wB*fb2.w;
            a3.x += wB*fb3.x; a3.y += wB*fb3.y; a3.z += wB*fb3.z; a3.w += wB*fb3.w;
            a4.x += wB*fb4.x; a4.y += wB*fb4.y; a4.z += wB*fb4.z; a4.w += wB*fb4.w;

            iA = nA; vA = nvA; vB = nvB;
            diA = ndiA; fiA = nfiA; diB = ndiB; fiB = nfiB;
        } while (vA);
    }

    // ---- Epilogue: LDS transpose-reduce ----
    // Write: lane (slot,ll) owns chunks {4j+ll}; chunk k lives at float offset
    // slot*SSTRIDE + 4k. All offsets 16B-aligned (SSTRIDE*4B = 336 = 16*21).
    {
        float* wb = &lds_buf[wave][slot * SSTRIDE + 4 * ll];
        *reinterpret_cast<float4*>(wb +  0) = a0;    // chunk ll
        *reinterpret_cast<float4*>(wb + 16) = a1;    // chunk ll+4
        *reinterpret_cast<float4*>(wb + 32) = a2;    // chunk ll+8
        *reinterpret_cast<float4*>(wb + 48) = a3;    // chunk ll+12
        *reinterpret_cast<float4*>(wb + 64) = a4;    // chunk ll+16
    }
    // Read: group g = lane>>5 sums slots g*8..g*8+7 of chunk c = lane&31
    // (active only for c < 20). Same-wave RAW: LDS ops retire in program
    // order within a wave and the compiler inserts the lgkmcnt wait;
    // region is wave-private so no __syncthreads needed.
    const int g = lane >> 5;
    const int c = lane & 31;
    float4 r = make_float4(0.f, 0.f, 0.f, 0.f);
    if (c < 20) {
        const float* rp = &lds_buf[wave][g * 8 * SSTRIDE + c * 4];
        #pragma unroll
        for (int t = 0; t < 8; ++t) {
            const float4 v = *reinterpret_cast<const float4*>(rp + t * SSTRIDE);
            r.x += v.x; r.y += v.y; r.z += v.z; r.w += v.w;
        }
    }
    // Merge the two slot-halves: lanes 0..19 get lanes 32..51's partial.
    // Must run at top level (both groups active in the shfl).
    r.x += __shfl_xor(r.x, 32, 64);
    r.y += __shfl_xor(r.y, 32, 64);
    r.z += __shfl_xor(r.z, 32, 64);
    r.w += __shfl_xor(r.w, 32, 64);

    if (lane < 20) {
        *reinterpret_cast<float4*>(out + (size_t)bin * CHN + lane * 4) = r;
    }
}

extern "C" void kernel_launch(void* const* d_in, const int* in_sizes, int n_in,
                              void* d_out, int out_size, void* d_ws, size_t ws_size,
                              hipStream_t stream) {
    const float* depth = (const float*)d_in[0];
    const float* feat  = (const float*)d_in[1];
    const int*   rd    = (const int*)d_in[2];
    const int*   rf    = (const int*)d_in[3];
    const int*   rb    = (const int*)d_in[4];
    // d_in[5], d_in[6] (interval_starts/lengths) unused per reference; d_in[7] scalar total_bev.
    float* out = (float*)d_out;

    const int P = in_sizes[2];
    const int total_bev = out_size / CHN;   // 40000

    int* seg = (int*)d_ws;                  // total_bev+1 ints, rewritten fully every call

    const int quads = (P + 3) / 4;
    seg_starts_kernel<<<(quads + 255) / 256, 256, 0, stream>>>(rb, seg, P, total_bev);
    bev_pool_kernel<<<(total_bev + 3) / 4, 256, 0, stream>>>(depth, feat, rd, rf, seg,
                                                             out, total_bev);
}